// Round 8
// baseline (943.466 us; speedup 1.0000x reference)
//
#include <hip/hip_runtime.h>
#include <cstdint>
#include <cstddef>

typedef unsigned short u16;
typedef unsigned int u32;
typedef __bf16 bf16x8 __attribute__((ext_vector_type(8)));
typedef float f32x4 __attribute__((ext_vector_type(4)));

#define NBLK 768   // 3 blocks/CU; capacity is 4-5/CU (VGPR 88, LDS 33KB) -> co-resident

// fp32 -> bf16 round-to-nearest-even (inputs finite)
__device__ inline u16 f2b(float f) {
    uint32_t u = __builtin_bit_cast(uint32_t, f);
    u += 0x7FFFu + ((u >> 16) & 1u);
    return (u16)(u >> 16);
}

// async global->LDS DMA, 16B per lane; lds dst is wave-uniform base + lane*16
__device__ inline void gl2lds16(const u16* g, u16* l) {
    __builtin_amdgcn_global_load_lds(
        (const __attribute__((address_space(1))) void*)g,
        (__attribute__((address_space(3))) void*)l, 16, 0, 0);
}

// ---------------- NT GEMM body: C = A (MxK) * B^T, B stored [N][K] -----------
// Software-pipelined dbuf LDS, 1 barrier/iter, DMA(k+1) issued before MFMA(k).
// EPI 0: C bf16 = acc
// EPI 2: causal mask + exp -> P bf16, atomicAdd row sums into lrow
// EPI 3: C fp32 = acc / lrow[row]
template<int EPI>
__device__ __forceinline__ void gemm_body(
    u16* __restrict__ smem,   // 16384 u16 = 32 KB: A0 | A1 | B0 | B1
    const u16* __restrict__ A, int lda,
    const u16* __restrict__ B, int ldb,
    char* __restrict__ Cb, int ldc,
    int m0, int n0, int Kloc, float* __restrict__ lrow) {
    constexpr int BK = 32;
    const int tid = threadIdx.x;
    const int lane = tid & 63, wave = tid >> 6;
    const int wm = wave >> 1, wn = wave & 1;       // 2x2 wave grid, 64x64 per wave
    const int fl = lane & 15, fh = lane >> 4;

    const int q0 = wave * 2;
    const int srow = lane >> 2, skoff = (lane & 3) * 8;
    const u16* ApL0 = A + (size_t)(m0 + q0 * 16 + srow) * lda + skoff;
    const u16* ApL1 = ApL0 + (size_t)16 * lda;
    const u16* BpL0 = B + (size_t)(n0 + q0 * 16 + srow) * ldb + skoff;
    const u16* BpL1 = BpL0 + (size_t)16 * ldb;

    u16* const Ab[2] = { smem, smem + 4096 };
    u16* const Bb[2] = { smem + 8192, smem + 12288 };

    auto issue = [&](int buf, int k0) {
        gl2lds16(ApL0 + k0, Ab[buf] + q0 * 512);
        gl2lds16(ApL1 + k0, Ab[buf] + q0 * 512 + 512);
        gl2lds16(BpL0 + k0, Bb[buf] + q0 * 512);
        gl2lds16(BpL1 + k0, Bb[buf] + q0 * 512 + 512);
    };

    const f32x4 vzero = {0.f, 0.f, 0.f, 0.f};
    f32x4 acc[4][4];
    #pragma unroll
    for (int i = 0; i < 4; ++i)
        #pragma unroll
        for (int j = 0; j < 4; ++j) acc[i][j] = vzero;

    issue(0, 0);
    int buf = 0;
    for (int k0 = 0; k0 < Kloc; k0 += BK, buf ^= 1) {
        __syncthreads();                       // publishes `buf` (drains its DMA)
        if (k0 + BK < Kloc) issue(buf ^ 1, k0 + BK);   // prefetch next tile
        bf16x8 af[4], bfr[4];
        #pragma unroll
        for (int t = 0; t < 4; ++t) {
            af[t]  = *(const bf16x8*)&Ab[buf][(wm * 64 + t * 16 + fl) * BK + fh * 8];
            bfr[t] = *(const bf16x8*)&Bb[buf][(wn * 64 + t * 16 + fl) * BK + fh * 8];
        }
        #pragma unroll
        for (int mt = 0; mt < 4; ++mt)
            #pragma unroll
            for (int nt = 0; nt < 4; ++nt)
                acc[mt][nt] = __builtin_amdgcn_mfma_f32_16x16x32_bf16(
                    af[mt], bfr[nt], acc[mt][nt], 0, 0, 0);
    }

    if (EPI == 0) {
        u16* Cp = (u16*)Cb;
        #pragma unroll
        for (int mt = 0; mt < 4; ++mt)
            #pragma unroll
            for (int nt = 0; nt < 4; ++nt)
                #pragma unroll
                for (int r = 0; r < 4; ++r) {
                    int row = m0 + wm * 64 + mt * 16 + fh * 4 + r;
                    int col = n0 + wn * 64 + nt * 16 + fl;
                    Cp[(size_t)row * ldc + col] = f2b(acc[mt][nt][r]);
                }
    } else if (EPI == 2) {
        u16* Cp = (u16*)Cb;
        #pragma unroll
        for (int mt = 0; mt < 4; ++mt)
            #pragma unroll
            for (int r = 0; r < 4; ++r) {
                int row = m0 + wm * 64 + mt * 16 + fh * 4 + r;
                float part = 0.f;
                #pragma unroll
                for (int nt = 0; nt < 4; ++nt) {
                    int col = n0 + wn * 64 + nt * 16 + fl;
                    float p = (col <= row) ? __expf(acc[mt][nt][r]) : 0.f;
                    part += p;
                    Cp[(size_t)row * ldc + col] = f2b(p);
                }
                #pragma unroll
                for (int off = 1; off < 16; off <<= 1)
                    part += __shfl_xor(part, off, 64);
                if (fl == 0) atomicAdd(lrow + row, part);
            }
    } else {
        float* Cp = (float*)Cb;
        #pragma unroll
        for (int mt = 0; mt < 4; ++mt)
            #pragma unroll
            for (int r = 0; r < 4; ++r) {
                int row = m0 + wm * 64 + mt * 16 + fh * 4 + r;
                float inv = 1.0f / lrow[row];
                #pragma unroll
                for (int nt = 0; nt < 4; ++nt) {
                    int col = n0 + wn * 64 + nt * 16 + fl;
                    Cp[(size_t)row * ldc + col] = acc[mt][nt][r] * inv;
                }
            }
    }
}

// ---- persistent mega-kernel: 4 phases, job-steal queues, device-scope
//      software grid barriers (all NBLK blocks co-resident by construction) ---
// ctrl[0..3]: job counters per phase; ctrl[4..6]: barrier arrive counters.
__global__ __launch_bounds__(256, 3)
void mega_kernel(const float* __restrict__ x,
                 const float* __restrict__ Wq, const float* __restrict__ Wk,
                 const float* __restrict__ Wv, float* __restrict__ out,
                 u16* __restrict__ xb, u16* __restrict__ QKWT,
                 u16* __restrict__ WvT, u16* __restrict__ QK,
                 u16* __restrict__ Vt, u16* __restrict__ P,
                 float* __restrict__ l, u32* ctrl) {
    __shared__ __align__(16) u16 smem[16384];
    __shared__ int jobLds;
    const int tid = threadIdx.x;

    auto nextjob = [&](int phase) -> int {
        if (tid == 0) jobLds = (int)atomicAdd(&ctrl[phase], 1u);
        __syncthreads();                       // also separates jobs' smem use
        int j = jobLds;
        __syncthreads();
        return j;
    };
    auto gbar = [&](int idx) {
        __syncthreads();
        __threadfence();                       // release: publish my writes
        if (tid == 0) {
            atomicAdd(&ctrl[idx], 1u);
            while (atomicAdd(&ctrl[idx], 0u) < NBLK) __builtin_amdgcn_s_sleep(8);
        }
        __syncthreads();
        __threadfence();                       // acquire: see others' writes
    };

    // ---- phase 0: x convert (2048 jobs) + W transpose (3072) + zero l (2) ---
    for (;;) {
        int j = nextjob(0);
        if (j >= 5122) break;
        if (j < 2048) {
            size_t base = (size_t)j * 4096;
            #pragma unroll
            for (int r = 0; r < 4; ++r) {
                size_t i = base + (size_t)(r * 256 + tid) * 4;
                float4 v = *(const float4*)(x + i);
                uint2 pack;
                pack.x = (u32)f2b(v.x) | ((u32)f2b(v.y) << 16);
                pack.y = (u32)f2b(v.z) | ((u32)f2b(v.w) << 16);
                *(uint2*)(xb + i) = pack;
            }
        } else if (j < 5120) {
            const int tb = j - 2048;
            const int z = tb >> 10, rem = tb & 1023;
            const int by = (rem >> 5) * 32, bx = (rem & 31) * 32;
            const float* W = (z == 0) ? Wq : ((z == 1) ? Wk : Wv);
            u16* dst = (z == 0) ? QKWT : ((z == 1) ? QKWT + 1024 * 1024 : WvT);
            const float scale = (z == 0) ? 0.03125f : 1.0f;  // fold 1/sqrt(1024)
            u16 (*t)[33] = (u16(*)[33])smem;
            const int tx = tid & 31, ty = tid >> 5;
            #pragma unroll
            for (int r = 0; r < 32; r += 8)
                t[ty + r][tx] = f2b(W[(size_t)(by + ty + r) * 1024 + bx + tx] * scale);
            __syncthreads();
            #pragma unroll
            for (int r = 0; r < 32; r += 8)
                dst[(size_t)(bx + ty + r) * 1024 + (by + tx)] = t[tx][ty + r];
        } else {
            size_t base = (size_t)(j - 5120) * 4096;
            #pragma unroll
            for (int r = 0; r < 4; ++r)
                *(float4*)(l + base + (size_t)(r * 256 + tid) * 4) =
                    make_float4(0.f, 0.f, 0.f, 0.f);
        }
    }
    gbar(4);

    // ---- phase 1: projections. QK [8192][2048] (1024 jobs) + V^T (512) -----
    for (;;) {
        int j = nextjob(1);
        if (j >= 1536) break;
        if (j < 1024) {
            int it = j >> 4, jt = j & 15;
            gemm_body<0>(smem, xb, 1024, QKWT, 1024, (char*)QK, 2048,
                         it * 128, jt * 128, 1024, nullptr);
        } else {
            int b = j - 1024, it = b >> 6, jt = b & 63;
            gemm_body<0>(smem, WvT, 1024, xb, 1024, (char*)Vt, 8192,
                         it * 128, jt * 128, 1024, nullptr);
        }
    }
    gbar(5);

    // ---- phase 2: scores, compact triangle, heavy (large it) first ----------
    for (;;) {
        int j = nextjob(2);
        if (j >= 544) break;
        const int z = j & 3;
        int t = j >> 2, it = 15, jt = 0;
        for (int i = 15; i >= 0; --i) {       // descending-it triangular map
            int n = i + 1;
            if (t < n) { it = i; jt = t; break; }
            t -= n;
        }
        const u16* Qz = QK + (size_t)z * 2048 * 2048;   // Q cols [0,1024)
        gemm_body<2>(smem, Qz, 2048, Qz + 1024, 2048,
                     (char*)(P + (size_t)z * 2048 * 2048), 2048,
                     it * 128, jt * 128, 1024, l + (size_t)z * 2048);
    }
    gbar(6);

    // ---- phase 3: O = (P/l) @ V, causal K-extent, heavy-first ---------------
    for (;;) {
        int j = nextjob(3);
        if (j >= 512) break;
        const int z = j & 3, r = j >> 2;
        const int it = 15 - (r >> 3), jt = r & 7;
        gemm_body<3>(smem, P + (size_t)z * 2048 * 2048, 2048,
                     Vt + (size_t)z * 2048, 8192,
                     (char*)(out + (size_t)z * 2048 * 1024), 1024,
                     it * 128, jt * 128, (it + 1) * 128, l + (size_t)z * 2048);
    }
}

extern "C" void kernel_launch(void* const* d_in, const int* in_sizes, int n_in,
                              void* d_out, int out_size, void* d_ws, size_t ws_size,
                              hipStream_t stream) {
    (void)in_sizes; (void)n_in; (void)out_size; (void)ws_size;
    const float* x  = (const float*)d_in[0];
    const float* Wq = (const float*)d_in[1];
    const float* Wk = (const float*)d_in[2];
    const float* Wv = (const float*)d_in[3];
    float* out = (float*)d_out;

    const size_t MB = 1u << 20;
    char* ws = (char*)d_ws;
    u16* xb   = (u16*)(ws);              // [8192][1024] bf16       16 MB
    u16* QKWT = (u16*)(ws + 16 * MB);    // [2048][1024] (WqT*s | WkT) 4 MB
    u16* WvT  = (u16*)(ws + 20 * MB);    // [1024][1024]             2 MB
    u16* QK   = (u16*)(ws + 22 * MB);    // [8192][2048] (Q|K)      32 MB
    u16* Vt   = (u16*)(ws + 54 * MB);    // V^T [1024][8192]        16 MB
    u16* P    = (u16*)(ws + 70 * MB);    // exp(S) [4][2048][2048]  32 MB
    float* l  = (float*)(ws + 102 * MB); // row sums [4][2048]      32 KB
    u32* ctrl = (u32*)(ws + 103 * MB);   // job + barrier counters  64 B

    hipMemsetAsync(ctrl, 0, 64, stream);
    mega_kernel<<<NBLK, 256, 0, stream>>>(x, Wq, Wk, Wv, out,
                                          xb, QKWT, WvT, QK, Vt, P, l, ctrl);
}